// Round 6
// baseline (3545.469 us; speedup 1.0000x reference)
//
#include <hip/hip_runtime.h>
#include <hip/hip_fp16.h>

typedef _Float16 f16;
typedef _Float16 f16x8 __attribute__((ext_vector_type(8)));
typedef float    f32x4 __attribute__((ext_vector_type(4)));
typedef unsigned short ushort;
typedef unsigned int uint;
typedef ushort ushort4v __attribute__((ext_vector_type(4)));

__device__ __forceinline__ float sigm(float x) { return 1.f / (1.f + __expf(-x)); }
__device__ __forceinline__ float reluf(float x) { return x > 0.f ? x : 0.f; }
__device__ __forceinline__ float h2f(ushort u) { return (float)__builtin_bit_cast(f16, u); }
__device__ __forceinline__ ushort f2h(float v) { return __builtin_bit_cast(ushort, (f16)v); }

#define LDRLX(p)    __hip_atomic_load((p), __ATOMIC_RELAXED, __HIP_MEMORY_SCOPE_AGENT)
#define STRLX(p, v) __hip_atomic_store((p), (v), __ATOMIC_RELAXED, __HIP_MEMORY_SCOPE_AGENT)
#define MFMA16(a, b, c) __builtin_amdgcn_mfma_f32_16x16x32_f16((a), (b), (c), 0, 0, 0)

// ---------------- pack B for MFMA b-frag layout (validated R1-R5)
template <int KF>
__global__ void pack_bsw(const float* __restrict__ B, f16* __restrict__ dst, int N) {
  int id = blockIdx.x * 256 + threadIdx.x;
  int total = KF * 32 * N;
  if (id >= total) return;
  int j  = id & 7;
  int L  = (id >> 3) & 63;
  int r  = id >> 9;
  int kf = r & (KF - 1);
  int c  = r / KF;
  int k  = kf * 32 + ((L >> 4) * 8) + j;
  int n  = c * 16 + (L & 15);
  dst[id] = (f16)B[k * N + n];
}

// ---------------- xW GEMM v2: block = 16 seqs x 4 timesteps of one group.
// Para (MODE 0): X[g][t][bb2][gate4][u128][s16]; Title (MODE 1): X[g][t][gate4][u128][s16]
template <int Sx, int K, int KF, int N, int NC, int MODE>
__global__ __launch_bounds__(256) void gemm_xw(const int* __restrict__ tok,
                                               const float* __restrict__ emb,
                                               const f16* __restrict__ Bsw,
                                               const float* __restrict__ bias,
                                               f16* __restrict__ X) {
  __shared__ int tokLds[64];
  __shared__ f16x8 bLds[8 * 64];
  const int tid = threadIdx.x;
  const int blk = blockIdx.x;
  const int g  = (MODE == 0) ? (blk >> 7) : (blk >> 4);
  const int t0 = (MODE == 0) ? ((blk & 127) * 4) : ((blk & 15) * 4);
  if (tid < 64) {
    int wv = tid >> 4, rho = tid & 15;
    tokLds[tid] = tok[(g * 16 + rho) * Sx + t0 + wv];
  }
  __syncthreads();
  const int wave = tid >> 6, lane = tid & 63;
  const int quad = lane >> 4, l16 = lane & 15;

  f16x8 a[KF];
  {
    const float* arow = emb + (long)tokLds[wave * 16 + l16] * K + quad * 8;
#pragma unroll
    for (int kf = 0; kf < KF; kf++) {
      float4 v0 = *(const float4*)(arow + kf * 32);
      float4 v1 = *(const float4*)(arow + kf * 32 + 4);
      f16x8 tv;
      tv[0] = (f16)v0.x; tv[1] = (f16)v0.y; tv[2] = (f16)v0.z; tv[3] = (f16)v0.w;
      tv[4] = (f16)v1.x; tv[5] = (f16)v1.y; tv[6] = (f16)v1.z; tv[7] = (f16)v1.w;
      a[kf] = tv;
    }
  }
  const int t = t0 + wave;
  const f16x8* Bfrag = (const f16x8*)Bsw;
  for (int c = 0; c < NC; c++) {
    for (int i = tid; i < KF * 64; i += 256) bLds[i] = Bfrag[c * KF * 64 + i];
    __syncthreads();
    f32x4 acc = {0.f, 0.f, 0.f, 0.f};
#pragma unroll
    for (int kf = 0; kf < KF; kf++)
      acc = MFMA16(a[kf], bLds[kf * 64 + lane], acc);
    const int col = c * 16 + l16;
    const float bc = bias[col];
    uint2 pk;
    pk.x = (uint)f2h(acc[0] + bc) | ((uint)f2h(acc[1] + bc) << 16);
    pk.y = (uint)f2h(acc[2] + bc) | ((uint)f2h(acc[3] + bc) << 16);
    size_t base;
    if (MODE == 0) {
      int gm = col >> 8, bbx = (col >> 7) & 1, u_loc = col & 127;
      base = ((((size_t)(g * 512 + t) * 2 + bbx) * 4 + gm) * 2048) + u_loc * 16 + quad * 4;
    } else {
      int gm = col >> 7, u_loc = col & 127;
      base = (((size_t)(g * 64 + t) * 4 + gm) * 2048) + u_loc * 16 + quad * 4;
    }
    *(uint2*)(X + base) = pk;
    __syncthreads();
  }
}

// ---------------- init: zero tag ring [g][slot8][bb2][2048]
__global__ void init_ring(uint* __restrict__ ring) {
  int i = blockIdx.x * 256 + threadIdx.x;
  if (i < 8 * 8 * 2 * 2048) ring[i] = 0u;
}

// ---------------- P0: paragraph L0, 16 blocks (g=blk&7, bb=blk>>3), reg weights
struct P0Args {
  const f16* xp2;
  const f16* U0f;
  uint* ring;
  f16* h0seq;   // [((g*512+t)*16+s)*256+u]
};

__global__ __launch_bounds__(256, 1) void recur_p0(P0Args A) {
  __shared__ f16 h0buf[2][16 * 264];  // [parity][s*264 + u]
  const int tid = threadIdx.x;
  const int w = tid >> 6, lane = tid & 63;
  const int quad = lane >> 4, l16 = lane & 15;
  const int g = blockIdx.x & 7, bb = blockIdx.x >> 3;

  // all 8 col-tiles' weights in registers (256 VGPR)
  const f16x8* U0v = (const f16x8*)A.U0f;
  f16x8 wreg[2][4][8];
#pragma unroll
  for (int j2 = 0; j2 < 2; j2++)
#pragma unroll
    for (int gm = 0; gm < 4; gm++) {
      const int ct = gm * 16 + bb * 8 + 2 * w + j2;
#pragma unroll
      for (int kf = 0; kf < 8; kf++)
        wreg[j2][gm][kf] = U0v[(ct * 8 + kf) * 64 + lane];
    }
  for (int idx = tid; idx < 16 * 264; idx += 256) h0buf[0][idx] = (f16)0.f;
  float c0[2][4] = {};
  const uint2* xq2 = (const uint2*)A.xp2;
  const int pollU = tid >> 1, pollS = (tid & 1) * 8;
  const int myU = 32 * w + l16;  // +16*j2
  __syncthreads();

  for (int t = 0; t < 512; t++) {
    // x(t): 8 coalesced uint2 loads (issued early, consumed after MFMA)
    uint2 xv[2][4];
    const size_t xstep = (((size_t)(g * 512 + t) * 2 + bb) * 4) * 512;
#pragma unroll
    for (int j2 = 0; j2 < 2; j2++)
#pragma unroll
      for (int gm = 0; gm < 4; gm++)
        xv[j2][gm] = xq2[xstep + gm * 512 + (myU + 16 * j2) * 4 + quad];
    // poll peer h(t-1): tag t in slot (t+7)&7
    {
      uint* rs = A.ring + ((((size_t)g * 8 + ((t + 7) & 7)) * 2 + (bb ^ 1)) * 2048);
      const uint tag = (uint)t;
      uint pv[8];
#pragma unroll
      for (int j = 0; j < 8; j++) pv[j] = LDRLX(rs + pollU * 16 + pollS + j);
      for (;;) {
        bool ok = true;
#pragma unroll
        for (int j = 0; j < 8; j++)
          if ((pv[j] >> 16) != tag) { pv[j] = LDRLX(rs + pollU * 16 + pollS + j); ok = false; }
        if (ok) break;
        __builtin_amdgcn_s_sleep(1);
      }
#pragma unroll
      for (int j = 0; j < 8; j++)
        h0buf[t & 1][(pollS + j) * 264 + (bb ^ 1) * 128 + pollU] =
            __builtin_bit_cast(f16, (ushort)(pv[j] & 0xffffu));
    }
    __syncthreads();
    // dump own half of h(t-1) to h0seq (coalesced via LDS)
    if (t > 0) {
      const int s = tid >> 4, c16 = tid & 15;
      uint4 v = *(const uint4*)&h0buf[t & 1][s * 264 + bb * 128 + c16 * 8];
      *(uint4*)&A.h0seq[((size_t)(g * 512 + (t - 1)) * 16 + s) * 256 + bb * 128 + c16 * 8] = v;
    }
    f16x8 af[8];
#pragma unroll
    for (int kf = 0; kf < 8; kf++)
      af[kf] = *(const f16x8*)&h0buf[t & 1][l16 * 264 + kf * 32 + quad * 8];
    f32x4 z[2][4];
#pragma unroll
    for (int j2 = 0; j2 < 2; j2++)
#pragma unroll
      for (int gm = 0; gm < 4; gm++) {
        f32x4 zz = {0.f, 0.f, 0.f, 0.f};
#pragma unroll
        for (int kf = 0; kf < 8; kf++) zz = MFMA16(af[kf], wreg[j2][gm][kf], zz);
        z[j2][gm] = zz;
      }
    uint* rw = A.ring + ((((size_t)g * 8 + (t & 7)) * 2 + bb) * 2048);
#pragma unroll
    for (int j2 = 0; j2 < 2; j2++) {
      ushort4v xi = __builtin_bit_cast(ushort4v, xv[j2][0]);
      ushort4v xf = __builtin_bit_cast(ushort4v, xv[j2][1]);
      ushort4v xg = __builtin_bit_cast(ushort4v, xv[j2][2]);
      ushort4v xo = __builtin_bit_cast(ushort4v, xv[j2][3]);
      const int u = bb * 128 + myU + 16 * j2;
#pragma unroll
      for (int r = 0; r < 4; r++) {
        float gi = sigm(z[j2][0][r] + h2f(xi[r]));
        float ff = sigm(z[j2][1][r] + h2f(xf[r]));
        float gg = reluf(z[j2][2][r] + h2f(xg[r]));
        float oo = sigm(z[j2][3][r] + h2f(xo[r]));
        c0[j2][r] = ff * c0[j2][r] + gi * gg;
        float h = oo * reluf(c0[j2][r]);
        ushort hb = f2h(h);
        h0buf[(t + 1) & 1][(quad * 4 + r) * 264 + u] = __builtin_bit_cast(f16, hb);
        STRLX(rw + (myU + 16 * j2) * 16 + quad * 4 + r, ((uint)(t + 1) << 16) | (uint)hb);
      }
    }
  }
  __syncthreads();
  {  // final dump t=511 (h in buf[0])
    const int s = tid >> 4, c16 = tid & 15;
    uint4 v = *(const uint4*)&h0buf[0][s * 264 + bb * 128 + c16 * 8];
    *(uint4*)&A.h0seq[((size_t)(g * 512 + 511) * 16 + s) * 256 + bb * 128 + c16 * 8] = v;
  }
}

// ---------------- P1: paragraph L1, 8 blocks x 512 thr, one barrier/step
struct P1Args {
  const f16* h0seq;
  const f16 *W1f, *U1f;
  const float* pl1_b;
  f16* h1seq;    // [((g*512+t)*16+s)*128+u]
};

__global__ __launch_bounds__(512, 1) void recur_p1(P1Args A) {
  __shared__ f16 U1lds[65536];          // 128 KB
  __shared__ f16 h0buf[2][16 * 264];    // 16.9 KB
  __shared__ f16 h1db[2][16 * 136];     // 8.7 KB
  const int tid = threadIdx.x;
  const int w = tid >> 6, lane = tid & 63;
  const int quad = lane >> 4, l16 = lane & 15;
  const int g = blockIdx.x;

  {
    const uint4* src = (const uint4*)A.U1f;
    uint4* dst = (uint4*)U1lds;
    for (int idx = tid; idx < 8192; idx += 512) dst[idx] = src[idx];
  }
  const f16x8* W1v = (const f16x8*)A.W1f;
  f16x8 wreg[4][8];
  float b1[4];
#pragma unroll
  for (int gm = 0; gm < 4; gm++) {
#pragma unroll
    for (int kf = 0; kf < 8; kf++)
      wreg[gm][kf] = W1v[((w + 8 * gm) * 8 + kf) * 64 + lane];
    b1[gm] = A.pl1_b[gm * 128 + 16 * w + l16];
  }
  for (int idx = tid; idx < 16 * 136; idx += 512) h1db[0][idx] = (f16)0.f;
  float c1[4] = {0.f, 0.f, 0.f, 0.f};

  const uint4* hsrc = (const uint4*)A.h0seq + (size_t)g * 512 * 512;
  const f16x8* U1v = (const f16x8*)U1lds;
  const int sS = tid >> 5, cS = tid & 31;
  uint4 cur = hsrc[tid];
  __syncthreads();

  for (int t = 0; t < 512; t++) {
    uint4 nxt = hsrc[(size_t)(t + 1 < 512 ? t + 1 : t) * 512 + tid];
    *(uint4*)&h0buf[t & 1][sS * 264 + cS * 8] = cur;
    __syncthreads();
    if (t > 0) {  // dump h1(t-1) coalesced
      uint2 v = *(const uint2*)&h1db[t & 1][sS * 136 + cS * 4];
      *(uint2*)&A.h1seq[((size_t)(g * 512 + (t - 1)) * 16 + sS) * 128 + cS * 4] = v;
    }
    f16x8 af0[8], af1[4];
#pragma unroll
    for (int kf = 0; kf < 8; kf++)
      af0[kf] = *(const f16x8*)&h0buf[t & 1][l16 * 264 + kf * 32 + quad * 8];
#pragma unroll
    for (int kf = 0; kf < 4; kf++)
      af1[kf] = *(const f16x8*)&h1db[t & 1][l16 * 136 + kf * 32 + quad * 8];
    f32x4 z[4];
#pragma unroll
    for (int gm = 0; gm < 4; gm++) {
      f32x4 zz = {0.f, 0.f, 0.f, 0.f};
#pragma unroll
      for (int kf = 0; kf < 8; kf++) zz = MFMA16(af0[kf], wreg[gm][kf], zz);
#pragma unroll
      for (int kf = 0; kf < 4; kf++)
        zz = MFMA16(af1[kf], U1v[((w + 8 * gm) * 4 + kf) * 64 + lane], zz);
      z[gm] = zz;
    }
    const int u = 16 * w + l16;
#pragma unroll
    for (int r = 0; r < 4; r++) {
      float gi = sigm(z[0][r] + b1[0]);
      float ff = sigm(z[1][r] + b1[1]);
      float gg = reluf(z[2][r] + b1[2]);
      float oo = sigm(z[3][r] + b1[3]);
      c1[r] = ff * c1[r] + gi * gg;
      h1db[(t + 1) & 1][(quad * 4 + r) * 136 + u] = (f16)(oo * reluf(c1[r]));
    }
    cur = nxt;
  }
  __syncthreads();
  {
    uint2 v = *(const uint2*)&h1db[0][sS * 136 + cS * 4];
    *(uint2*)&A.h1seq[((size_t)(g * 512 + 511) * 16 + sS) * 128 + cS * 4] = v;
  }
}

// ---------------- P2 + Title: 16 blocks x 256 thr
struct P2TArgs {
  const f16* h1seq;
  const f16 *W2f, *U2f;
  const float* pl2_b;
  const float *pd0W, *pd0b, *pd1W, *pd1b, *pd2W, *pd2b;
  const f16* xt2;
  const f16 *U0tf, *W1tf, *U1tf;
  const float* tl1_b;
  const float *td0W, *td0b, *td1W, *td1b, *td2W, *td2b;
  float* feat;
};

__global__ __launch_bounds__(256, 1) void recur_p2t(P2TArgs A) {
  __shared__ __align__(16) char smem[157184];
  const int tid = threadIdx.x;
  const int w = tid >> 6, lane = tid & 63;
  const int quad = lane >> 4, l16 = lane & 15;
  const int blk = blockIdx.x;
  float* zmA = (float*)(smem + 144384);   // 16 x 132 f32
  float* zmB = (float*)(smem + 152832);   // 16 x 68  f32

  if (blk < 8) {
    // ========== paragraph L2 + dense tail ==========
    const int g = blk;
    f16* h1cur = (f16*)(smem + 126976);       // [2][16*136]
    f16* h2db  = (f16*)(smem + 139776);       // [2][16*72]
    const f16x8* W2v = (const f16x8*)A.W2f;
    const f16x8* U2v = (const f16x8*)A.U2f;
    f16x8 wB[4][4], wU[4][2];
    float b2[4];
#pragma unroll
    for (int gm = 0; gm < 4; gm++) {
#pragma unroll
      for (int kf = 0; kf < 4; kf++) wB[gm][kf] = W2v[((w + 4 * gm) * 4 + kf) * 64 + lane];
#pragma unroll
      for (int kf = 0; kf < 2; kf++) wU[gm][kf] = U2v[((w + 4 * gm) * 2 + kf) * 64 + lane];
      b2[gm] = A.pl2_b[gm * 64 + 16 * w + l16];
    }
    for (int idx = tid; idx < 16 * 72; idx += 256) h2db[idx] = (f16)0.f;
    float c2[4] = {0.f, 0.f, 0.f, 0.f};
    const uint4* hsrc = (const uint4*)A.h1seq + (size_t)g * 512 * 256;
    const int sS = tid >> 4, cS = tid & 15;
    uint4 cur = hsrc[tid];
    __syncthreads();

    for (int t = 0; t < 512; t++) {
      uint4 nxt = hsrc[(size_t)(t + 1 < 512 ? t + 1 : t) * 256 + tid];
      *(uint4*)&h1cur[(t & 1) * 2176 + sS * 136 + cS * 8] = cur;
      __syncthreads();
      f16x8 af0[4], af1[2];
#pragma unroll
      for (int kf = 0; kf < 4; kf++)
        af0[kf] = *(const f16x8*)&h1cur[(t & 1) * 2176 + l16 * 136 + kf * 32 + quad * 8];
#pragma unroll
      for (int kf = 0; kf < 2; kf++)
        af1[kf] = *(const f16x8*)&h2db[(t & 1) * 1152 + l16 * 72 + kf * 32 + quad * 8];
      f32x4 z[4];
#pragma unroll
      for (int gm = 0; gm < 4; gm++) {
        f32x4 zz = {0.f, 0.f, 0.f, 0.f};
#pragma unroll
        for (int kf = 0; kf < 4; kf++) zz = MFMA16(af0[kf], wB[gm][kf], zz);
#pragma unroll
        for (int kf = 0; kf < 2; kf++) zz = MFMA16(af1[kf], wU[gm][kf], zz);
        z[gm] = zz;
      }
      const int u = 16 * w + l16;
#pragma unroll
      for (int r = 0; r < 4; r++) {
        float gi = sigm(z[0][r] + b2[0]);
        float ff = sigm(z[1][r] + b2[1]);
        float gg = reluf(z[2][r] + b2[2]);
        float oo = sigm(z[3][r] + b2[3]);
        c2[r] = ff * c2[r] + gi * gg;
        h2db[((t + 1) & 1) * 1152 + (quad * 4 + r) * 72 + u] = (f16)(oo * reluf(c2[r]));
      }
      cur = nxt;
    }
    __syncthreads();
    const f16* hf = h2db;  // parity 0
#pragma unroll 1
    for (int e = 0; e < 8; e++) {
      const int idx = tid + 256 * e, sq = idx >> 7, j = idx & 127;
      float a = A.pd0b[j];
      for (int k = 0; k < 64; k++) a += (float)hf[sq * 72 + k] * A.pd0W[k * 128 + j];
      zmA[sq * 132 + j] = reluf(a);
    }
    __syncthreads();
#pragma unroll 1
    for (int e = 0; e < 4; e++) {
      const int idx = tid + 256 * e, sq = idx >> 6, j = idx & 63;
      float a = A.pd1b[j];
      for (int k = 0; k < 128; k++) a += zmA[sq * 132 + k] * A.pd1W[k * 64 + j];
      zmB[sq * 68 + j] = reluf(a);
    }
    __syncthreads();
#pragma unroll 1
    for (int e = 0; e < 2; e++) {
      const int idx = tid + 256 * e, sq = idx >> 5, j = idx & 31;
      float a = A.pd2b[j];
      for (int k = 0; k < 64; k++) a += zmB[sq * 68 + k] * A.pd2W[k * 32 + j];
      A.feat[(g * 16 + sq) * 64 + 32 + j] = a;
    }
  } else {
    // ========== title full stack ==========
    const int g = blk - 8;
    f16* wldsT = (f16*)smem;                  // 128 KB U0t b-frags
    f16* h0db  = (f16*)(smem + 131072);       // [2][16*136]
    f16* h1db  = (f16*)(smem + 139776);       // [2][16*72]
    {
      const uint4* src = (const uint4*)A.U0tf;
      uint4* dst = (uint4*)wldsT;
      for (int idx = tid; idx < 8192; idx += 256) dst[idx] = src[idx];
    }
    const f16x8* W1tv = (const f16x8*)A.W1tf;
    const f16x8* U1tv = (const f16x8*)A.U1tf;
    f16x8 wB[4][4], wU[4][2];
    float bt[4];
#pragma unroll
    for (int gm = 0; gm < 4; gm++) {
#pragma unroll
      for (int kf = 0; kf < 4; kf++) wB[gm][kf] = W1tv[((w + 4 * gm) * 4 + kf) * 64 + lane];
#pragma unroll
      for (int kf = 0; kf < 2; kf++) wU[gm][kf] = U1tv[((w + 4 * gm) * 2 + kf) * 64 + lane];
      bt[gm] = A.tl1_b[gm * 64 + 16 * w + l16];
    }
    for (int idx = tid; idx < 16 * 136; idx += 256) h0db[idx] = (f16)0.f;
    for (int idx = tid; idx < 16 * 72; idx += 256) h1db[idx] = (f16)0.f;
    float c0t[2][4] = {}, c1t[4] = {};
    const uint2* xq2 = (const uint2*)A.xt2;
    const f16x8* wldv = (const f16x8*)wldsT;
    const int myU = 32 * w + l16;
    __syncthreads();

    for (int t = 0; t < 64; t++) {
      uint2 xv[2][4];
      const size_t xstep = ((size_t)(g * 64 + t) * 4) * 512;
#pragma unroll
      for (int j2 = 0; j2 < 2; j2++)
#pragma unroll
        for (int gm = 0; gm < 4; gm++)
          xv[j2][gm] = xq2[xstep + gm * 512 + (myU + 16 * j2) * 4 + quad];
      // ---- L0t
      f16x8 af[4];
#pragma unroll
      for (int kf = 0; kf < 4; kf++)
        af[kf] = *(const f16x8*)&h0db[(t & 1) * 2176 + l16 * 136 + kf * 32 + quad * 8];
#pragma unroll
      for (int j2 = 0; j2 < 2; j2++) {
        const int ut = 2 * w + j2;
        f32x4 z[4];
#pragma unroll
        for (int gm = 0; gm < 4; gm++) {
          f32x4 zz = {0.f, 0.f, 0.f, 0.f};
#pragma unroll
          for (int kf = 0; kf < 4; kf++)
            zz = MFMA16(af[kf], wldv[((ut + 8 * gm) * 4 + kf) * 64 + lane], zz);
          z[gm] = zz;
        }
        ushort4v xi = __builtin_bit_cast(ushort4v, xv[j2][0]);
        ushort4v xf = __builtin_bit_cast(ushort4v, xv[j2][1]);
        ushort4v xg = __builtin_bit_cast(ushort4v, xv[j2][2]);
        ushort4v xo = __builtin_bit_cast(ushort4v, xv[j2][3]);
#pragma unroll
        for (int r = 0; r < 4; r++) {
          float gi = sigm(z[0][r] + h2f(xi[r]));
          float ff = sigm(z[1][r] + h2f(xf[r]));
          float gg = reluf(z[2][r] + h2f(xg[r]));
          float oo = sigm(z[3][r] + h2f(xo[r]));
          c0t[j2][r] = ff * c0t[j2][r] + gi * gg;
          h0db[((t + 1) & 1) * 2176 + (quad * 4 + r) * 136 + 16 * ut + l16] =
              (f16)(oo * reluf(c0t[j2][r]));
        }
      }
      __syncthreads();
      // ---- L1t
      f16x8 afC[4], afU[2];
#pragma unroll
      for (int kf = 0; kf < 4; kf++)
        afC[kf] = *(const f16x8*)&h0db[((t + 1) & 1) * 2176 + l16 * 136 + kf * 32 + quad * 8];
#pragma unroll
      for (int kf = 0; kf < 2; kf++)
        afU[kf] = *(const f16x8*)&h1db[(t & 1) * 1152 + l16 * 72 + kf * 32 + quad * 8];
      f32x4 z[4];
#pragma unroll
      for (int gm = 0; gm < 4; gm++) {
        f32x4 zz = {0.f, 0.f, 0.f, 0.f};
#pragma unroll
        for (int kf = 0; kf < 4; kf++) zz = MFMA16(afC[kf], wB[gm][kf], zz);
#pragma unroll
        for (int kf = 0; kf < 2; kf++) zz = MFMA16(afU[kf], wU[gm][kf], zz);
        z[gm] = zz;
      }
#pragma unroll
      for (int r = 0; r < 4; r++) {
        float gi = sigm(z[0][r] + bt[0]);
        float ff = sigm(z[1][r] + bt[1]);
        float gg = reluf(z[2][r] + bt[2]);
        float oo = sigm(z[3][r] + bt[3]);
        c1t[r] = ff * c1t[r] + gi * gg;
        h1db[((t + 1) & 1) * 1152 + (quad * 4 + r) * 72 + 16 * w + l16] =
            (f16)(oo * reluf(c1t[r]));
      }
      __syncthreads();
    }
    const f16* hf = h1db;  // parity 0
#pragma unroll 1
    for (int e = 0; e < 8; e++) {
      const int idx = tid + 256 * e, sq = idx >> 7, j = idx & 127;
      float a = A.td0b[j];
      for (int k = 0; k < 64; k++) a += (float)hf[sq * 72 + k] * A.td0W[k * 128 + j];
      zmA[sq * 132 + j] = reluf(a);
    }
    __syncthreads();
#pragma unroll 1
    for (int e = 0; e < 4; e++) {
      const int idx = tid + 256 * e, sq = idx >> 6, j = idx & 63;
      float a = A.td1b[j];
      for (int k = 0; k < 128; k++) a += zmA[sq * 132 + k] * A.td1W[k * 64 + j];
      zmB[sq * 68 + j] = reluf(a);
    }
    __syncthreads();
#pragma unroll 1
    for (int e = 0; e < 2; e++) {
      const int idx = tid + 256 * e, sq = idx >> 5, j = idx & 31;
      float a = A.td2b[j];
      for (int k = 0; k < 64; k++) a += zmB[sq * 68 + k] * A.td2W[k * 32 + j];
      A.feat[(g * 16 + sq) * 64 + j] = a;
    }
  }
}

// ---------------- head
__global__ __launch_bounds__(256) void head_kernel(const float* __restrict__ feat,
    const float* __restrict__ L0W, const float* __restrict__ L0b,
    const float* __restrict__ L1W, const float* __restrict__ L1b,
    const float* __restrict__ L2W, const float* __restrict__ L2b,
    const float* __restrict__ L3W, const float* __restrict__ L3b,
    float* __restrict__ out) {
  __shared__ float xb[512];
  __shared__ float y0[2048];
  __shared__ float y1[1024];
  __shared__ float y2[512];
  const int tid = threadIdx.x;
  for (int idx = tid; idx < 512; idx += 256) {
    int b = idx >> 6, d = idx & 63;
    float s = 0.f;
    for (int n = 0; n < 16; n++) s += feat[(b * 16 + n) * 64 + d];
    xb[idx] = s * (1.f / 16.f);
  }
  __syncthreads();
  for (int idx = tid; idx < 2048; idx += 256) {
    int b = idx >> 8, j = idx & 255;
    float a = L0b[j];
    for (int k = 0; k < 64; k++) a += xb[b * 64 + k] * L0W[k * 256 + j];
    y0[idx] = reluf(a);
  }
  __syncthreads();
  for (int idx = tid; idx < 1024; idx += 256) {
    int b = idx >> 7, j = idx & 127;
    float a = L1b[j];
    for (int k = 0; k < 256; k++) a += y0[b * 256 + k] * L1W[k * 128 + j];
    y1[idx] = reluf(a);
  }
  __syncthreads();
  for (int idx = tid; idx < 512; idx += 256) {
    int b = idx >> 6, j = idx & 63;
    float a = L2b[j];
    for (int k = 0; k < 128; k++) a += y1[b * 128 + k] * L2W[k * 64 + j];
    y2[idx] = reluf(a);
  }
  __syncthreads();
  {
    int b = tid >> 5, j = tid & 31;
    float a = L3b[j];
    for (int k = 0; k < 64; k++) a += y2[b * 64 + k] * L3W[k * 32 + j];
    out[b * 32 + j] = 1.f / (1.f + __expf(-a));
  }
}

extern "C" void kernel_launch(void* const* d_in, const int* in_sizes, int n_in,
                              void* d_out, int out_size, void* d_ws, size_t ws_size,
                              hipStream_t stream) {
  const int*   t_tok = (const int*)d_in[0];
  const int*   p_tok = (const int*)d_in[1];
  const float* emb_t = (const float*)d_in[2];
  const float* emb_p = (const float*)d_in[3];
  const float* tl0_W = (const float*)d_in[4];
  const float* tl0_U = (const float*)d_in[5];
  const float* tl0_b = (const float*)d_in[6];
  const float* tl1_W = (const float*)d_in[7];
  const float* tl1_U = (const float*)d_in[8];
  const float* tl1_b = (const float*)d_in[9];
  const float* td0_W = (const float*)d_in[10];
  const float* td0_b = (const float*)d_in[11];
  const float* td1_W = (const float*)d_in[12];
  const float* td1_b = (const float*)d_in[13];
  const float* td2_W = (const float*)d_in[14];
  const float* td2_b = (const float*)d_in[15];
  const float* pl0_W = (const float*)d_in[16];
  const float* pl0_U = (const float*)d_in[17];
  const float* pl0_b = (const float*)d_in[18];
  const float* pl1_W = (const float*)d_in[19];
  const float* pl1_U = (const float*)d_in[20];
  const float* pl1_b = (const float*)d_in[21];
  const float* pl2_W = (const float*)d_in[22];
  const float* pl2_U = (const float*)d_in[23];
  const float* pl2_b = (const float*)d_in[24];
  const float* pd0_W = (const float*)d_in[25];
  const float* pd0_b = (const float*)d_in[26];
  const float* pd1_W = (const float*)d_in[27];
  const float* pd1_b = (const float*)d_in[28];
  const float* pd2_W = (const float*)d_in[29];
  const float* pd2_b = (const float*)d_in[30];
  const float* L0_W  = (const float*)d_in[31];
  const float* L0_b  = (const float*)d_in[32];
  const float* L1_W  = (const float*)d_in[33];
  const float* L1_b  = (const float*)d_in[34];
  const float* L2_W  = (const float*)d_in[35];
  const float* L2_b  = (const float*)d_in[36];
  const float* L3_W  = (const float*)d_in[37];
  const float* L3_b  = (const float*)d_in[38];

  char* ws = (char*)d_ws;
  size_t off = 0;
  auto alloc = [&](size_t bytes) {
    void* ptr = ws + off;
    off += (bytes + 255) & ~(size_t)255;
    return ptr;
  };
  f16* xp2  = (f16*)alloc((size_t)8 * 512 * 2 * 4 * 2048 * 2);   // 128 MB
  f16* xt2  = (f16*)alloc((size_t)8 * 64 * 4 * 2048 * 2);        // 8 MB
  f16* Bp   = (f16*)alloc((size_t)256 * 1024 * 2);
  f16* Bt   = (f16*)alloc((size_t)128 * 512 * 2);
  f16* U0f  = (f16*)alloc((size_t)256 * 1024 * 2);
  f16* W1f  = (f16*)alloc((size_t)256 * 512 * 2);
  f16* U1f  = (f16*)alloc((size_t)128 * 512 * 2);
  f16* W2f  = (f16*)alloc((size_t)128 * 256 * 2);
  f16* U2f  = (f16*)alloc((size_t)64 * 256 * 2);
  f16* U0tf = (f16*)alloc((size_t)128 * 512 * 2);
  f16* W1tf = (f16*)alloc((size_t)128 * 256 * 2);
  f16* U1tf = (f16*)alloc((size_t)64 * 256 * 2);
  uint* ring = (uint*)alloc((size_t)8 * 8 * 2 * 2048 * 4);       // 1 MB
  f16* h0seq = (f16*)alloc((size_t)8 * 512 * 16 * 256 * 2);      // 32 MB
  f16* h1seq = (f16*)alloc((size_t)8 * 512 * 16 * 128 * 2);      // 16 MB
  float* feat = (float*)alloc((size_t)128 * 64 * 4);

  init_ring<<<1024, 256, 0, stream>>>(ring);

  pack_bsw<8><<<1024, 256, 0, stream>>>(pl0_W, Bp, 1024);
  pack_bsw<4><<<256, 256, 0, stream>>>(tl0_W, Bt, 512);
  pack_bsw<8><<<1024, 256, 0, stream>>>(pl0_U, U0f, 1024);
  pack_bsw<8><<<512, 256, 0, stream>>>(pl1_W, W1f, 512);
  pack_bsw<4><<<256, 256, 0, stream>>>(pl1_U, U1f, 512);
  pack_bsw<4><<<128, 256, 0, stream>>>(pl2_W, W2f, 256);
  pack_bsw<2><<<64, 256, 0, stream>>>(pl2_U, U2f, 256);
  pack_bsw<4><<<256, 256, 0, stream>>>(tl0_U, U0tf, 512);
  pack_bsw<4><<<128, 256, 0, stream>>>(tl1_W, W1tf, 256);
  pack_bsw<2><<<64, 256, 0, stream>>>(tl1_U, U1tf, 256);
  gemm_xw<512, 256, 8, 1024, 64, 0><<<1024, 256, 0, stream>>>(p_tok, emb_p, Bp, pl0_b, xp2);
  gemm_xw<64, 128, 4, 512, 32, 1><<<128, 256, 0, stream>>>(t_tok, emb_t, Bt, tl0_b, xt2);

  P0Args a0;
  a0.xp2 = xp2; a0.U0f = U0f; a0.ring = ring; a0.h0seq = h0seq;
  recur_p0<<<16, 256, 0, stream>>>(a0);

  P1Args a1;
  a1.h0seq = h0seq; a1.W1f = W1f; a1.U1f = U1f; a1.pl1_b = pl1_b; a1.h1seq = h1seq;
  recur_p1<<<8, 512, 0, stream>>>(a1);

  P2TArgs a2;
  a2.h1seq = h1seq; a2.W2f = W2f; a2.U2f = U2f; a2.pl2_b = pl2_b;
  a2.pd0W = pd0_W; a2.pd0b = pd0_b; a2.pd1W = pd1_W; a2.pd1b = pd1_b;
  a2.pd2W = pd2_W; a2.pd2b = pd2_b;
  a2.xt2 = xt2; a2.U0tf = U0tf; a2.W1tf = W1tf; a2.U1tf = U1tf; a2.tl1_b = tl1_b;
  a2.td0W = td0_W; a2.td0b = td0_b; a2.td1W = td1_W; a2.td1b = td1_b;
  a2.td2W = td2_W; a2.td2b = td2_b;
  a2.feat = feat;
  recur_p2t<<<16, 256, 0, stream>>>(a2);

  head_kernel<<<1, 256, 0, stream>>>(feat, L0_W, L0_b, L1_W, L1_b, L2_W, L2_b,
                                     L3_W, L3_b, (float*)d_out);
}

// Round 7
// 1897.026 us; speedup vs baseline: 1.8690x; 1.8690x over previous
//
#include <hip/hip_runtime.h>
#include <hip/hip_fp16.h>

typedef _Float16 f16;
typedef _Float16 f16x8 __attribute__((ext_vector_type(8)));
typedef float    f32x4 __attribute__((ext_vector_type(4)));
typedef unsigned short ushort;
typedef unsigned int uint;
typedef unsigned long long u64;

__device__ __forceinline__ float sigm(float x) { return 1.f / (1.f + __expf(-x)); }
__device__ __forceinline__ float reluf(float x) { return x > 0.f ? x : 0.f; }
__device__ __forceinline__ float h2f(ushort u) { return (float)__builtin_bit_cast(f16, u); }
__device__ __forceinline__ ushort f2h(float v) { return __builtin_bit_cast(ushort, (f16)v); }

#define LDRLX(p)    __hip_atomic_load((p), __ATOMIC_RELAXED, __HIP_MEMORY_SCOPE_AGENT)
#define STRLX(p, v) __hip_atomic_store((p), (v), __ATOMIC_RELAXED, __HIP_MEMORY_SCOPE_AGENT)
#define MFMA16(a, b, c) __builtin_amdgcn_mfma_f32_16x16x32_f16((a), (b), (c), 0, 0, 0)

__device__ __forceinline__ void wait_ge(uint* p, uint need) {
  while (LDRLX(p) < need) __builtin_amdgcn_s_sleep(2);
}
__device__ __forceinline__ u64 ldr64(const u64* p) {
  return __hip_atomic_load(p, __ATOMIC_RELAXED, __HIP_MEMORY_SCOPE_AGENT);
}
__device__ __forceinline__ void str64(u64* p, u64 v) {
  __hip_atomic_store(p, v, __ATOMIC_RELAXED, __HIP_MEMORY_SCOPE_AGENT);
}

// ---------------- pack B for MFMA b-frag layout (validated R1-R6)
template <int KF>
__global__ void pack_bsw(const float* __restrict__ B, f16* __restrict__ dst, int N) {
  int id = blockIdx.x * 256 + threadIdx.x;
  int total = KF * 32 * N;
  if (id >= total) return;
  int j  = id & 7;
  int L  = (id >> 3) & 63;
  int r  = id >> 9;
  int kf = r & (KF - 1);
  int c  = r / KF;
  int k  = kf * 32 + ((L >> 4) * 8) + j;
  int n  = c * 16 + (L & 15);
  dst[id] = (f16)B[k * N + n];
}

// ---------------- xW GEMM. MODE0 para: X[g][t][gate4][u256][s16]. MODE1 title:
// X[g][t][gate4][u128][s16].  (s = quad*4+r rows of the MFMA C tile = seq index)
template <int Sx, int K, int KF, int N, int NC, int MODE>
__global__ __launch_bounds__(256) void gemm_xw(const int* __restrict__ tok,
                                               const float* __restrict__ emb,
                                               const f16* __restrict__ Bsw,
                                               const float* __restrict__ bias,
                                               f16* __restrict__ X) {
  __shared__ int tokLds[64];
  __shared__ f16x8 bLds[8 * 64];
  const int tid = threadIdx.x;
  const int blk = blockIdx.x;
  const int g  = (MODE == 0) ? (blk >> 7) : (blk >> 4);
  const int t0 = (MODE == 0) ? ((blk & 127) * 4) : ((blk & 15) * 4);
  if (tid < 64) {
    int wv = tid >> 4, rho = tid & 15;
    tokLds[tid] = tok[(g * 16 + rho) * Sx + t0 + wv];
  }
  __syncthreads();
  const int wave = tid >> 6, lane = tid & 63;
  const int quad = lane >> 4, l16 = lane & 15;

  f16x8 a[KF];
  {
    const float* arow = emb + (long)tokLds[wave * 16 + l16] * K + quad * 8;
#pragma unroll
    for (int kf = 0; kf < KF; kf++) {
      float4 v0 = *(const float4*)(arow + kf * 32);
      float4 v1 = *(const float4*)(arow + kf * 32 + 4);
      f16x8 tv;
      tv[0] = (f16)v0.x; tv[1] = (f16)v0.y; tv[2] = (f16)v0.z; tv[3] = (f16)v0.w;
      tv[4] = (f16)v1.x; tv[5] = (f16)v1.y; tv[6] = (f16)v1.z; tv[7] = (f16)v1.w;
      a[kf] = tv;
    }
  }
  const int t = t0 + wave;
  const f16x8* Bfrag = (const f16x8*)Bsw;
  for (int c = 0; c < NC; c++) {
    for (int i = tid; i < KF * 64; i += 256) bLds[i] = Bfrag[c * KF * 64 + i];
    __syncthreads();
    f32x4 acc = {0.f, 0.f, 0.f, 0.f};
#pragma unroll
    for (int kf = 0; kf < KF; kf++)
      acc = MFMA16(a[kf], bLds[kf * 64 + lane], acc);
    const int col = c * 16 + l16;
    const float bc = bias[col];
    uint2 pk;
    pk.x = (uint)f2h(acc[0] + bc) | ((uint)f2h(acc[1] + bc) << 16);
    pk.y = (uint)f2h(acc[2] + bc) | ((uint)f2h(acc[3] + bc) << 16);
    size_t base;
    if (MODE == 0) {
      int gm = col >> 8, u = col & 255;
      base = (((size_t)(g * 512 + t) * 4 + gm) * 4096) + u * 16 + quad * 4;
    } else {
      int gm = col >> 7, u = col & 127;
      base = (((size_t)(g * 64 + t) * 4 + gm) * 2048) + u * 16 + quad * 4;
    }
    *(uint2*)(X + base) = pk;
    __syncthreads();
  }
}

// ---------------- init counters (must re-zero every replay)
__global__ void init_cnt(uint* __restrict__ cnt) {
  int i = blockIdx.x * 256 + threadIdx.x;
  if (i < 96 * 16) cnt[i] = 0u;
}

// ---------------- pipelined persistent recurrence: 96 blocks x 256 thr
// role = blk>>3, g = blk&7. roles: 0-3 paraL0(bb), 4-7 paraL1(bn), 8 paraL2,
// 9-10 titleL0(bb), 11 titleL1. Rings: relaxed 8B tagged publishes + per-role
// step counters (cnt, stride 16 uints). Tag stored after __syncthreads (vmcnt
// drain). Back-pressure every 4 steps keeps 8-slot rings safe.
struct RP {
  const f16 *xp2, *xt2;
  const f16 *U0f, *W1f, *U1f, *W2f, *U2f, *U0tf, *W1tf, *U1tf;
  const float *pl1_b, *pl2_b, *tl1_b;
  const float *pd0W, *pd0b, *pd1W, *pd1b, *pd2W, *pd2b;
  const float *td0W, *td0b, *td1W, *td1b, *td2W, *td2b;
  uint *h0r, *h1r, *h0tr, *cnt;
  float* feat;
};

__global__ __launch_bounds__(256, 1) void recur_pipe(RP A) {
  __shared__ __align__(16) char smem[147968];
  const int tid = threadIdx.x;
  const int w = tid >> 6, lane = tid & 63;
  const int quad = lane >> 4, l16 = lane & 15;
  const int blk = blockIdx.x;
  const int role = blk >> 3, g = blk & 7;
  uint* mytag = A.cnt + (role * 8 + g) * 16;

  if (role < 4) {
    // ================= paragraph L0: units 64*bb.. , weights 128KB LDS =======
    const int bb = role;
    f16* wlds = (f16*)smem;                 // [gm4][wv4][kf8][64] f16x8
    f16* hb   = (f16*)(smem + 131072);      // [2][16*264]
    {
      const uint4* U0q = (const uint4*)A.U0f;
      uint4* wq = (uint4*)wlds;
      for (int idx = tid; idx < 8192; idx += 256) {
        int gm = idx >> 11, r = idx & 2047, wv = r >> 9, kf = (r >> 6) & 7, ln = r & 63;
        wq[idx] = U0q[((gm * 16 + 4 * bb + wv) * 8 + kf) * 64 + ln];
      }
    }
    for (int idx = tid; idx < 4224; idx += 256) hb[idx] = (f16)0.f;
    float c0[4] = {0.f, 0.f, 0.f, 0.f};
    uint* ringg = A.h0r + (size_t)g * 8 * 4096;
    int pp[3]; { int q = 0; for (int p = 0; p < 4; p++) if (p != bb) pp[q++] = p; }
    const uint2* xq2 = (const uint2*)A.xp2;
    const f16x8* wv8 = (const f16x8*)wlds;
    const int myu = 64 * bb + 16 * w + l16;
    __syncthreads();

    for (int t = 0; t < 512; t++) {
      uint2 xv[4];
      {
        size_t xb = ((size_t)(g * 512 + t) * 4) * 1024 + (size_t)myu * 4 + quad;
#pragma unroll
        for (int gm = 0; gm < 4; gm++) xv[gm] = xq2[xb + (size_t)gm * 1024];
      }
      if (t > 0) {
        for (int q = 0; q < 3; q++) wait_ge(A.cnt + (pp[q] * 8 + g) * 16, (uint)t);
        if ((t & 3) == 0) {
          uint need = t > 4 ? (uint)(t - 4) : 0u;
          for (int bn = 0; bn < 4; bn++) wait_ge(A.cnt + ((4 + bn) * 8 + g) * 16, need);
        }
        f16* dst = hb + (t & 1) * 4224;
        const int ul = tid >> 2, s0 = (tid & 3) * 4;
        for (int q = 0; q < 3; q++) {
          const u64* reg = (const u64*)(ringg + (((t + 7) & 7) * 4 + pp[q]) * 1024);
          u64 v = ldr64(reg + tid);
#pragma unroll
          for (int j = 0; j < 4; j++)
            dst[(s0 + j) * 264 + pp[q] * 64 + ul] = __builtin_bit_cast(f16, (ushort)(v >> (16 * j)));
        }
      }
      __syncthreads();
      f16x8 af[8];
#pragma unroll
      for (int kf = 0; kf < 8; kf++)
        af[kf] = *(const f16x8*)&hb[(t & 1) * 4224 + l16 * 264 + kf * 32 + quad * 8];
      f32x4 z[4];
#pragma unroll
      for (int gm = 0; gm < 4; gm++) {
        f32x4 zz = {0.f, 0.f, 0.f, 0.f};
#pragma unroll
        for (int kf = 0; kf < 8; kf++)
          zz = MFMA16(af[kf], wv8[((gm * 4 + w) * 8 + kf) * 64 + lane], zz);
        z[gm] = zz;
      }
      u64 xs[4];
#pragma unroll
      for (int gm = 0; gm < 4; gm++) xs[gm] = ((u64)xv[gm].y << 32) | xv[gm].x;
      ushort hs[4];
      f16* wbuf = hb + ((t + 1) & 1) * 4224;
#pragma unroll
      for (int r = 0; r < 4; r++) {
        float gi = sigm(z[0][r] + h2f((ushort)(xs[0] >> (16 * r))));
        float ff = sigm(z[1][r] + h2f((ushort)(xs[1] >> (16 * r))));
        float gg = reluf(z[2][r] + h2f((ushort)(xs[2] >> (16 * r))));
        float oo = sigm(z[3][r] + h2f((ushort)(xs[3] >> (16 * r))));
        c0[r] = ff * c0[r] + gi * gg;
        hs[r] = f2h(oo * reluf(c0[r]));
        wbuf[(quad * 4 + r) * 264 + myu] = __builtin_bit_cast(f16, hs[r]);
      }
      {
        u64 pv = (u64)hs[0] | ((u64)hs[1] << 16) | ((u64)hs[2] << 32) | ((u64)hs[3] << 48);
        u64* wreg = (u64*)(ringg + ((t & 7) * 4 + bb) * 1024);
        str64(wreg + (16 * w + l16) * 4 + quad, pv);
      }
      __syncthreads();                 // drains vmcnt (all waves) before tag
      if (tid == 0) STRLX(mytag, (uint)(t + 1));
    }
  } else if (role < 8) {
    // ================= paragraph L1: units 32*bn.., 96KB LDS weights ========
    const int bn = role - 4;
    f16* wlds = (f16*)smem;                  // W1 @0 (4096 x f16x8), U1 @4096
    f16* h0c  = (f16*)(smem + 98304);        // 16*264
    f16* h1b  = (f16*)(smem + 106752);       // [2][16*136]
    float* zL = (float*)(smem + 115456);     // 16*132
    {
      const uint4* W1q = (const uint4*)A.W1f;
      const uint4* U1q = (const uint4*)A.U1f;
      uint4* wq = (uint4*)wlds;
      for (int idx = tid; idx < 4096; idx += 256) {
        int gm = idx >> 10, r = idx & 1023, j2 = r >> 9, kf = (r >> 6) & 7, ln = r & 63;
        wq[idx] = W1q[((gm * 8 + bn * 2 + j2) * 8 + kf) * 64 + ln];
      }
      for (int idx = tid; idx < 2048; idx += 256) {
        int gm = idx >> 9, r = idx & 511, j2 = r >> 8, kf = (r >> 6) & 3, ln = r & 63;
        wq[4096 + idx] = U1q[((gm * 8 + bn * 2 + j2) * 4 + kf) * 64 + ln];
      }
    }
    for (int idx = tid; idx < 2176; idx += 256) h1b[idx] = (f16)0.f;
    float c1[2] = {0.f, 0.f};
    float bth[4];
    { int un = tid & 31; for (int gm = 0; gm < 4; gm++) bth[gm] = A.pl1_b[gm * 128 + 32 * bn + un]; }
    uint* h0rg = A.h0r + (size_t)g * 8 * 4096;
    uint* h1rg = A.h1r + (size_t)g * 8 * 1024;
    int pp[3]; { int q = 0; for (int p = 0; p < 4; p++) if (p != bn) pp[q++] = p; }
    const f16x8* wv8 = (const f16x8*)wlds;
    __syncthreads();

    for (int t = 0; t < 512; t++) {
      for (int p = 0; p < 4; p++) wait_ge(A.cnt + (p * 8 + g) * 16, (uint)(t + 1));
      if (t > 0)
        for (int q = 0; q < 3; q++) wait_ge(A.cnt + ((4 + pp[q]) * 8 + g) * 16, (uint)t);
      if ((t & 3) == 0) {
        uint need = t > 4 ? (uint)(t - 4) : 0u;
        wait_ge(A.cnt + (8 * 8 + g) * 16, need);
      }
      {
        const u64* base = (const u64*)(h0rg + (t & 7) * 4096);
#pragma unroll
        for (int e = 0; e < 4; e++) {
          int idx = tid + 256 * e;
          u64 v = ldr64(base + idx);
          int q = idx >> 8, r = idx & 255, ul = r >> 2, s0 = (r & 3) * 4;
#pragma unroll
          for (int j = 0; j < 4; j++)
            h0c[(s0 + j) * 264 + q * 64 + ul] = __builtin_bit_cast(f16, (ushort)(v >> (16 * j)));
        }
      }
      if (t > 0 && tid < 128) {
        f16* dst = h1b + (t & 1) * 2176;
        const u64* sbase = (const u64*)(h1rg + ((t + 7) & 7) * 1024);
        const int ul = tid >> 2, s0 = (tid & 3) * 4;
        for (int q = 0; q < 3; q++) {
          u64 v = ldr64(sbase + pp[q] * 128 + tid);
#pragma unroll
          for (int j = 0; j < 4; j++)
            dst[(s0 + j) * 136 + pp[q] * 32 + ul] = __builtin_bit_cast(f16, (ushort)(v >> (16 * j)));
        }
      }
      __syncthreads();
      f16x8 af0[8], af1[4];
#pragma unroll
      for (int kf = 0; kf < 8; kf++)
        af0[kf] = *(const f16x8*)&h0c[l16 * 264 + kf * 32 + quad * 8];
#pragma unroll
      for (int kf = 0; kf < 4; kf++)
        af1[kf] = *(const f16x8*)&h1b[(t & 1) * 2176 + l16 * 136 + kf * 32 + quad * 8];
#pragma unroll
      for (int j2 = 0; j2 < 2; j2++) {
        f32x4 zz = {0.f, 0.f, 0.f, 0.f};
#pragma unroll
        for (int kf = 0; kf < 8; kf++)
          zz = MFMA16(af0[kf], wv8[((w * 2 + j2) * 8 + kf) * 64 + lane], zz);
#pragma unroll
        for (int kf = 0; kf < 4; kf++)
          zz = MFMA16(af1[kf], wv8[4096 + ((w * 2 + j2) * 4 + kf) * 64 + lane], zz);
#pragma unroll
        for (int r = 0; r < 4; r++)
          zL[(quad * 4 + r) * 132 + w * 32 + j2 * 16 + l16] = zz[r];
      }
      __syncthreads();
      {
        int sq = tid >> 5, un = tid & 31;
        f16* dst = h1b + ((t + 1) & 1) * 2176;
#pragma unroll
        for (int e = 0; e < 2; e++) {
          int s = sq + 8 * e;
          float gi = sigm(zL[s * 132 + un] + bth[0]);
          float ff = sigm(zL[s * 132 + 32 + un] + bth[1]);
          float gg = reluf(zL[s * 132 + 64 + un] + bth[2]);
          float oo = sigm(zL[s * 132 + 96 + un] + bth[3]);
          c1[e] = ff * c1[e] + gi * gg;
          dst[s * 136 + 32 * bn + un] = (f16)(oo * reluf(c1[e]));
        }
      }
      __syncthreads();
      if (tid < 128) {
        const f16* src = h1b + ((t + 1) & 1) * 2176;
        int ul = tid >> 2, s0 = (tid & 3) * 4;
        u64 pv = 0;
#pragma unroll
        for (int j = 0; j < 4; j++)
          pv |= (u64)__builtin_bit_cast(ushort, src[(s0 + j) * 136 + 32 * bn + ul]) << (16 * j);
        str64((u64*)(h1rg + (t & 7) * 1024) + bn * 128 + tid, pv);
      }
      __syncthreads();
      if (tid == 0) STRLX(mytag, (uint)(t + 1));
    }
  } else if (role == 8) {
    // ================= paragraph L2 + dense tail ============================
    f16* wlds = (f16*)smem;                  // W2 @0 (4096 f16x8), U2 @4096
    f16* h1c  = (f16*)(smem + 98304);        // 16*136
    f16* h2db = (f16*)(smem + 102656);       // [2][16*72]
    {
      const uint4* W2q = (const uint4*)A.W2f;
      const uint4* U2q = (const uint4*)A.U2f;
      uint4* wq = (uint4*)wlds;
      for (int idx = tid; idx < 4096; idx += 256) wq[idx] = W2q[idx];
      for (int idx = tid; idx < 2048; idx += 256) wq[4096 + idx] = U2q[idx];
    }
    for (int idx = tid; idx < 1152; idx += 256) h2db[idx] = (f16)0.f;
    float c2[4] = {0.f, 0.f, 0.f, 0.f};
    float b2[4];
#pragma unroll
    for (int gm = 0; gm < 4; gm++) b2[gm] = A.pl2_b[gm * 64 + 16 * w + l16];
    uint* h1rg = A.h1r + (size_t)g * 8 * 1024;
    const f16x8* wv8 = (const f16x8*)wlds;
    __syncthreads();

    for (int t = 0; t < 512; t++) {
      for (int p = 0; p < 4; p++) wait_ge(A.cnt + ((4 + p) * 8 + g) * 16, (uint)(t + 1));
      {
        const u64* base = (const u64*)(h1rg + (t & 7) * 1024);
#pragma unroll
        for (int e = 0; e < 2; e++) {
          int idx = tid + 256 * e;
          u64 v = ldr64(base + idx);
          int q = idx >> 7, r = idx & 127, ul = r >> 2, s0 = (r & 3) * 4;
#pragma unroll
          for (int j = 0; j < 4; j++)
            h1c[(s0 + j) * 136 + q * 32 + ul] = __builtin_bit_cast(f16, (ushort)(v >> (16 * j)));
        }
      }
      __syncthreads();
      f16x8 af0[4], af1[2];
#pragma unroll
      for (int kf = 0; kf < 4; kf++)
        af0[kf] = *(const f16x8*)&h1c[l16 * 136 + kf * 32 + quad * 8];
#pragma unroll
      for (int kf = 0; kf < 2; kf++)
        af1[kf] = *(const f16x8*)&h2db[(t & 1) * 1152 + l16 * 72 + kf * 32 + quad * 8];
      f32x4 z[4];
#pragma unroll
      for (int gm = 0; gm < 4; gm++) {
        f32x4 zz = {0.f, 0.f, 0.f, 0.f};
#pragma unroll
        for (int kf = 0; kf < 4; kf++)
          zz = MFMA16(af0[kf], wv8[((gm * 4 + w) * 4 + kf) * 64 + lane], zz);
#pragma unroll
        for (int kf = 0; kf < 2; kf++)
          zz = MFMA16(af1[kf], wv8[4096 + ((gm * 4 + w) * 2 + kf) * 64 + lane], zz);
        z[gm] = zz;
      }
#pragma unroll
      for (int r = 0; r < 4; r++) {
        float gi = sigm(z[0][r] + b2[0]);
        float ff = sigm(z[1][r] + b2[1]);
        float gg = reluf(z[2][r] + b2[2]);
        float oo = sigm(z[3][r] + b2[3]);
        c2[r] = ff * c2[r] + gi * gg;
        h2db[((t + 1) & 1) * 1152 + (quad * 4 + r) * 72 + 16 * w + l16] = (f16)(oo * reluf(c2[r]));
      }
      __syncthreads();
      if (tid == 0) STRLX(mytag, (uint)(t + 1));
    }
    __syncthreads();
    // dense tail -> feat cols 32..63
    float* zmA = (float*)smem;                // 16*132
    float* zmB = (float*)(smem + 8448);       // 16*68
    const f16* hf = h2db;                     // parity 0
#pragma unroll 1
    for (int e = 0; e < 8; e++) {
      const int idx = tid + 256 * e, sq = idx >> 7, j = idx & 127;
      float a = A.pd0b[j];
      for (int k = 0; k < 64; k++) a += (float)hf[sq * 72 + k] * A.pd0W[k * 128 + j];
      zmA[sq * 132 + j] = reluf(a);
    }
    __syncthreads();
#pragma unroll 1
    for (int e = 0; e < 4; e++) {
      const int idx = tid + 256 * e, sq = idx >> 6, j = idx & 63;
      float a = A.pd1b[j];
      for (int k = 0; k < 128; k++) a += zmA[sq * 132 + k] * A.pd1W[k * 64 + j];
      zmB[sq * 68 + j] = reluf(a);
    }
    __syncthreads();
#pragma unroll 1
    for (int e = 0; e < 2; e++) {
      const int idx = tid + 256 * e, sq = idx >> 5, j = idx & 31;
      float a = A.pd2b[j];
      for (int k = 0; k < 64; k++) a += zmB[sq * 68 + k] * A.pd2W[k * 32 + j];
      A.feat[(g * 16 + sq) * 64 + 32 + j] = a;
    }
  } else if (role < 11) {
    // ================= title L0: units 64*bb.., 64KB LDS ====================
    const int bb = role - 9;
    f16* wlds = (f16*)smem;                  // [gm4][wv4][kf4][64]
    f16* hb   = (f16*)(smem + 65536);        // [2][16*136]
    {
      const uint4* U0tq = (const uint4*)A.U0tf;
      uint4* wq = (uint4*)wlds;
      for (int idx = tid; idx < 4096; idx += 256) {
        int gm = idx >> 10, r = idx & 1023, wv = r >> 8, kf = (r >> 6) & 3, ln = r & 63;
        wq[idx] = U0tq[((gm * 8 + 4 * bb + wv) * 4 + kf) * 64 + ln];
      }
    }
    for (int idx = tid; idx < 2176; idx += 256) hb[idx] = (f16)0.f;
    float c0[4] = {0.f, 0.f, 0.f, 0.f};
    uint* ringg = A.h0tr + (size_t)g * 8 * 1024;
    const uint2* xq2 = (const uint2*)A.xt2;
    const f16x8* wv8 = (const f16x8*)wlds;
    const int myu = 64 * bb + 16 * w + l16;
    const int pb = bb ^ 1;
    __syncthreads();

    for (int t = 0; t < 64; t++) {
      uint2 xv[4];
      {
        size_t xb = ((size_t)(g * 64 + t) * 4) * 512 + (size_t)myu * 4 + quad;
#pragma unroll
        for (int gm = 0; gm < 4; gm++) xv[gm] = xq2[xb + (size_t)gm * 512];
      }
      if (t > 0) {
        wait_ge(A.cnt + ((9 + pb) * 8 + g) * 16, (uint)t);
        if ((t & 3) == 0) {
          uint need = t > 4 ? (uint)(t - 4) : 0u;
          wait_ge(A.cnt + (11 * 8 + g) * 16, need);
        }
        const u64* reg = (const u64*)(ringg + (((t + 7) & 7) * 2 + pb) * 512);
        u64 v = ldr64(reg + tid);
        f16* dst = hb + (t & 1) * 2176;
        int ul = tid >> 2, s0 = (tid & 3) * 4;
#pragma unroll
        for (int j = 0; j < 4; j++)
          dst[(s0 + j) * 136 + pb * 64 + ul] = __builtin_bit_cast(f16, (ushort)(v >> (16 * j)));
      }
      __syncthreads();
      f16x8 af[4];
#pragma unroll
      for (int kf = 0; kf < 4; kf++)
        af[kf] = *(const f16x8*)&hb[(t & 1) * 2176 + l16 * 136 + kf * 32 + quad * 8];
      f32x4 z[4];
#pragma unroll
      for (int gm = 0; gm < 4; gm++) {
        f32x4 zz = {0.f, 0.f, 0.f, 0.f};
#pragma unroll
        for (int kf = 0; kf < 4; kf++)
          zz = MFMA16(af[kf], wv8[((gm * 4 + w) * 4 + kf) * 64 + lane], zz);
        z[gm] = zz;
      }
      u64 xs[4];
#pragma unroll
      for (int gm = 0; gm < 4; gm++) xs[gm] = ((u64)xv[gm].y << 32) | xv[gm].x;
      ushort hs[4];
      f16* wbuf = hb + ((t + 1) & 1) * 2176;
#pragma unroll
      for (int r = 0; r < 4; r++) {
        float gi = sigm(z[0][r] + h2f((ushort)(xs[0] >> (16 * r))));
        float ff = sigm(z[1][r] + h2f((ushort)(xs[1] >> (16 * r))));
        float gg = reluf(z[2][r] + h2f((ushort)(xs[2] >> (16 * r))));
        float oo = sigm(z[3][r] + h2f((ushort)(xs[3] >> (16 * r))));
        c0[r] = ff * c0[r] + gi * gg;
        hs[r] = f2h(oo * reluf(c0[r]));
        wbuf[(quad * 4 + r) * 136 + myu] = __builtin_bit_cast(f16, hs[r]);
      }
      {
        u64 pv = (u64)hs[0] | ((u64)hs[1] << 16) | ((u64)hs[2] << 32) | ((u64)hs[3] << 48);
        u64* wreg = (u64*)(ringg + ((t & 7) * 2 + bb) * 512);
        str64(wreg + (16 * w + l16) * 4 + quad, pv);
      }
      __syncthreads();
      if (tid == 0) STRLX(mytag, (uint)(t + 1));
    }
  } else {
    // ================= title L1 + dense tail ================================
    f16* wlds = (f16*)smem;                  // W1t @0, U1t @4096 (f16x8 units)
    f16* h0tc = (f16*)(smem + 98304);        // 16*136
    f16* h1db = (f16*)(smem + 102656);       // [2][16*72]
    {
      const uint4* W1tq = (const uint4*)A.W1tf;
      const uint4* U1tq = (const uint4*)A.U1tf;
      uint4* wq = (uint4*)wlds;
      for (int idx = tid; idx < 4096; idx += 256) wq[idx] = W1tq[idx];
      for (int idx = tid; idx < 2048; idx += 256) wq[4096 + idx] = U1tq[idx];
    }
    for (int idx = tid; idx < 1152; idx += 256) h1db[idx] = (f16)0.f;
    float c1[4] = {0.f, 0.f, 0.f, 0.f};
    float bt[4];
#pragma unroll
    for (int gm = 0; gm < 4; gm++) bt[gm] = A.tl1_b[gm * 64 + 16 * w + l16];
    uint* ringg = A.h0tr + (size_t)g * 8 * 1024;
    const f16x8* wv8 = (const f16x8*)wlds;
    __syncthreads();

    for (int t = 0; t < 64; t++) {
      wait_ge(A.cnt + (9 * 8 + g) * 16, (uint)(t + 1));
      wait_ge(A.cnt + (10 * 8 + g) * 16, (uint)(t + 1));
      {
        const u64* base = (const u64*)(ringg + (t & 7) * 1024);
#pragma unroll
        for (int e = 0; e < 2; e++) {
          int idx = tid + 256 * e;
          u64 v = ldr64(base + idx);
          int q = idx >> 8, r = idx & 255, ul = r >> 2, s0 = (r & 3) * 4;
#pragma unroll
          for (int j = 0; j < 4; j++)
            h0tc[(s0 + j) * 136 + q * 64 + ul] = __builtin_bit_cast(f16, (ushort)(v >> (16 * j)));
        }
      }
      __syncthreads();
      f16x8 af0[4], af1[2];
#pragma unroll
      for (int kf = 0; kf < 4; kf++)
        af0[kf] = *(const f16x8*)&h0tc[l16 * 136 + kf * 32 + quad * 8];
#pragma unroll
      for (int kf = 0; kf < 2; kf++)
        af1[kf] = *(const f16x8*)&h1db[(t & 1) * 1152 + l16 * 72 + kf * 32 + quad * 8];
      f32x4 z[4];
#pragma unroll
      for (int gm = 0; gm < 4; gm++) {
        f32x4 zz = {0.f, 0.f, 0.f, 0.f};
#pragma unroll
        for (int kf = 0; kf < 4; kf++)
          zz = MFMA16(af0[kf], wv8[((gm * 4 + w) * 4 + kf) * 64 + lane], zz);
#pragma unroll
        for (int kf = 0; kf < 2; kf++)
          zz = MFMA16(af1[kf], wv8[4096 + ((gm * 4 + w) * 2 + kf) * 64 + lane], zz);
        z[gm] = zz;
      }
#pragma unroll
      for (int r = 0; r < 4; r++) {
        float gi = sigm(z[0][r] + bt[0]);
        float ff = sigm(z[1][r] + bt[1]);
        float gg = reluf(z[2][r] + bt[2]);
        float oo = sigm(z[3][r] + bt[3]);
        c1[r] = ff * c1[r] + gi * gg;
        h1db[((t + 1) & 1) * 1152 + (quad * 4 + r) * 72 + 16 * w + l16] = (f16)(oo * reluf(c1[r]));
      }
      __syncthreads();
      if (tid == 0) STRLX(mytag, (uint)(t + 1));
    }
    __syncthreads();
    // dense tail -> feat cols 0..31
    float* zmA = (float*)smem;
    float* zmB = (float*)(smem + 8448);
    const f16* hf = h1db;                    // parity 0
#pragma unroll 1
    for (int e = 0; e < 8; e++) {
      const int idx = tid + 256 * e, sq = idx >> 7, j = idx & 127;
      float a = A.td0b[j];
      for (int k = 0; k < 64; k++) a += (float)hf[sq * 72 + k] * A.td0W[k * 128 + j];
      zmA[sq * 132 + j] = reluf(a);
    }
    __syncthreads();
#pragma unroll 1
    for (int e = 0; e < 4; e++) {
      const int idx = tid + 256 * e, sq = idx >> 6, j = idx & 63;
      float a = A.td1b[j];
      for (int k = 0; k < 128; k++) a += zmA[sq * 132 + k] * A.td1W[k * 64 + j];
      zmB[sq * 68 + j] = reluf(a);
    }
    __syncthreads();
#pragma unroll 1
    for (int e = 0; e < 2; e++) {
      const int idx = tid + 256 * e, sq = idx >> 5, j = idx & 31;
      float a = A.td2b[j];
      for (int k = 0; k < 64; k++) a += zmB[sq * 68 + k] * A.td2W[k * 32 + j];
      A.feat[(g * 16 + sq) * 64 + j] = a;
    }
  }
}

// ---------------- head
__global__ __launch_bounds__(256) void head_kernel(const float* __restrict__ feat,
    const float* __restrict__ L0W, const float* __restrict__ L0b,
    const float* __restrict__ L1W, const float* __restrict__ L1b,
    const float* __restrict__ L2W, const float* __restrict__ L2b,
    const float* __restrict__ L3W, const float* __restrict__ L3b,
    float* __restrict__ out) {
  __shared__ float xb[512];
  __shared__ float y0[2048];
  __shared__ float y1[1024];
  __shared__ float y2[512];
  const int tid = threadIdx.x;
  for (int idx = tid; idx < 512; idx += 256) {
    int b = idx >> 6, d = idx & 63;
    float s = 0.f;
    for (int n = 0; n < 16; n++) s += feat[(b * 16 + n) * 64 + d];
    xb[idx] = s * (1.f / 16.f);
  }
  __syncthreads();
  for (int idx = tid; idx < 2048; idx += 256) {
    int b = idx >> 8, j = idx & 255;
    float a = L0b[j];
    for (int k = 0; k < 64; k++) a += xb[b * 64 + k] * L0W[k * 256 + j];
    y0[idx] = reluf(a);
  }
  __syncthreads();
  for (int idx = tid; idx < 1024; idx += 256) {
    int b = idx >> 7, j = idx & 127;
    float a = L1b[j];
    for (int k = 0; k < 256; k++) a += y0[b * 256 + k] * L1W[k * 128 + j];
    y1[idx] = reluf(a);
  }
  __syncthreads();
  for (int idx = tid; idx < 512; idx += 256) {
    int b = idx >> 6, j = idx & 63;
    float a = L2b[j];
    for (int k = 0; k < 128; k++) a += y1[b * 128 + k] * L2W[k * 64 + j];
    y2[idx] = reluf(a);
  }
  __syncthreads();
  {
    int b = tid >> 5, j = tid & 31;
    float a = L3b[j];
    for (int k = 0; k < 64; k++) a += y2[b * 64 + k] * L3W[k * 32 + j];
    out[b * 32 + j] = 1.f / (1.f + __expf(-a));
  }
}

extern "C" void kernel_launch(void* const* d_in, const int* in_sizes, int n_in,
                              void* d_out, int out_size, void* d_ws, size_t ws_size,
                              hipStream_t stream) {
  const int*   t_tok = (const int*)d_in[0];
  const int*   p_tok = (const int*)d_in[1];
  const float* emb_t = (const float*)d_in[2];
  const float* emb_p = (const float*)d_in[3];
  const float* tl0_W = (const float*)d_in[4];
  const float* tl0_U = (const float*)d_in[5];
  const float* tl0_b = (const float*)d_in[6];
  const float* tl1_W = (const float*)d_in[7];
  const float* tl1_U = (const float*)d_in[8];
  const float* tl1_b = (const float*)d_in[9];
  const float* td0_W = (const float*)d_in[10];
  const float* td0_b = (const float*)d_in[11];
  const float* td1_W = (const float*)d_in[12];
  const float* td1_b = (const float*)d_in[13];
  const float* td2_W = (const float*)d_in[14];
  const float* td2_b = (const float*)d_in[15];
  const float* pl0_W = (const float*)d_in[16];
  const float* pl0_U = (const float*)d_in[17];
  const float* pl0_b = (const float*)d_in[18];
  const float* pl1_W = (const float*)d_in[19];
  const float* pl1_U = (const float*)d_in[20];
  const float* pl1_b = (const float*)d_in[21];
  const float* pl2_W = (const float*)d_in[22];
  const float* pl2_U = (const float*)d_in[23];
  const float* pl2_b = (const float*)d_in[24];
  const float* pd0_W = (const float*)d_in[25];
  const float* pd0_b = (const float*)d_in[26];
  const float* pd1_W = (const float*)d_in[27];
  const float* pd1_b = (const float*)d_in[28];
  const float* pd2_W = (const float*)d_in[29];
  const float* pd2_b = (const float*)d_in[30];
  const float* L0_W  = (const float*)d_in[31];
  const float* L0_b  = (const float*)d_in[32];
  const float* L1_W  = (const float*)d_in[33];
  const float* L1_b  = (const float*)d_in[34];
  const float* L2_W  = (const float*)d_in[35];
  const float* L2_b  = (const float*)d_in[36];
  const float* L3_W  = (const float*)d_in[37];
  const float* L3_b  = (const float*)d_in[38];

  char* ws = (char*)d_ws;
  size_t off = 0;
  auto alloc = [&](size_t bytes) {
    void* ptr = ws + off;
    off += (bytes + 255) & ~(size_t)255;
    return ptr;
  };
  f16* xp2  = (f16*)alloc((size_t)8 * 512 * 4 * 4096 * 2);     // 128 MB
  f16* xt2  = (f16*)alloc((size_t)8 * 64 * 4 * 2048 * 2);      // 8 MB
  f16* Bp   = (f16*)alloc((size_t)256 * 1024 * 2);
  f16* Bt   = (f16*)alloc((size_t)128 * 512 * 2);
  f16* U0f  = (f16*)alloc((size_t)256 * 1024 * 2);
  f16* W1f  = (f16*)alloc((size_t)256 * 512 * 2);
  f16* U1f  = (f16*)alloc((size_t)128 * 512 * 2);
  f16* W2f  = (f16*)alloc((size_t)128 * 256 * 2);
  f16* U2f  = (f16*)alloc((size_t)64 * 256 * 2);
  f16* U0tf = (f16*)alloc((size_t)128 * 512 * 2);
  f16* W1tf = (f16*)alloc((size_t)128 * 256 * 2);
  f16* U1tf = (f16*)alloc((size_t)64 * 256 * 2);
  uint* h0r  = (uint*)alloc((size_t)8 * 8 * 4 * 1024 * 4);     // 1 MB
  uint* h1r  = (uint*)alloc((size_t)8 * 8 * 4 * 256 * 4);      // 256 KB
  uint* h0tr = (uint*)alloc((size_t)8 * 8 * 2 * 512 * 4);      // 256 KB
  uint* cnt  = (uint*)alloc((size_t)96 * 16 * 4);
  float* feat = (float*)alloc((size_t)128 * 64 * 4);

  init_cnt<<<6, 256, 0, stream>>>(cnt);

  pack_bsw<8><<<1024, 256, 0, stream>>>(pl0_W, Bp, 1024);
  pack_bsw<4><<<256, 256, 0, stream>>>(tl0_W, Bt, 512);
  pack_bsw<8><<<1024, 256, 0, stream>>>(pl0_U, U0f, 1024);
  pack_bsw<8><<<512, 256, 0, stream>>>(pl1_W, W1f, 512);
  pack_bsw<4><<<256, 256, 0, stream>>>(pl1_U, U1f, 512);
  pack_bsw<4><<<128, 256, 0, stream>>>(pl2_W, W2f, 256);
  pack_bsw<2><<<64, 256, 0, stream>>>(pl2_U, U2f, 256);
  pack_bsw<4><<<256, 256, 0, stream>>>(tl0_U, U0tf, 512);
  pack_bsw<4><<<128, 256, 0, stream>>>(tl1_W, W1tf, 256);
  pack_bsw<2><<<64, 256, 0, stream>>>(tl1_U, U1tf, 256);
  gemm_xw<512, 256, 8, 1024, 64, 0><<<1024, 256, 0, stream>>>(p_tok, emb_p, Bp, pl0_b, xp2);
  gemm_xw<64, 128, 4, 512, 32, 1><<<128, 256, 0, stream>>>(t_tok, emb_t, Bt, tl0_b, xt2);

  RP ra;
  ra.xp2 = xp2; ra.xt2 = xt2;
  ra.U0f = U0f; ra.W1f = W1f; ra.U1f = U1f; ra.W2f = W2f; ra.U2f = U2f;
  ra.U0tf = U0tf; ra.W1tf = W1tf; ra.U1tf = U1tf;
  ra.pl1_b = pl1_b; ra.pl2_b = pl2_b; ra.tl1_b = tl1_b;
  ra.pd0W = pd0_W; ra.pd0b = pd0_b; ra.pd1W = pd1_W; ra.pd1b = pd1_b;
  ra.pd2W = pd2_W; ra.pd2b = pd2_b;
  ra.td0W = td0_W; ra.td0b = td0_b; ra.td1W = td1_W; ra.td1b = td1_b;
  ra.td2W = td2_W; ra.td2b = td2_b;
  ra.h0r = h0r; ra.h1r = h1r; ra.h0tr = h0tr; ra.cnt = cnt;
  ra.feat = feat;
  recur_pipe<<<96, 256, 0, stream>>>(ra);

  head_kernel<<<1, 256, 0, stream>>>(feat, L0_W, L0_b, L1_W, L1_b, L2_W, L2_b,
                                     L3_W, L3_b, (float*)d_out);
}